// Round 17
// baseline (421.325 us; speedup 1.0000x reference)
//
#include <hip/hip_runtime.h>
#include <math.h>

#define EPSV 1e-5f

typedef _Float16 f16x8 __attribute__((ext_vector_type(8)));
typedef _Float16 f16x4 __attribute__((ext_vector_type(4)));
typedef _Float16 f16x2 __attribute__((ext_vector_type(2)));
typedef float f32x4 __attribute__((ext_vector_type(4)));

// ---------------------------------------------------------------------------
// Kernel 0: weight prep -> split-fp16 (hi,lo) pairs.
// w2t[off][oc][ic] (9,64,32); w1p[oc][k32] taps 0-8, bias k=9;
// fwp[d][oc*56+pos] padded FC weights (pos 49..55 = 0) for the fused FC.
// ---------------------------------------------------------------------------
__global__ __launch_bounds__(256) void prep_weights(
    const float* __restrict__ w1, const float* __restrict__ b1,
    const float* __restrict__ w2, const float* __restrict__ fw,
    _Float16* __restrict__ w2t_hi, _Float16* __restrict__ w2t_lo,
    _Float16* __restrict__ fwp_hi, _Float16* __restrict__ fwp_lo,
    _Float16* __restrict__ w1p_hi, _Float16* __restrict__ w1p_lo)
{
    int idx = blockIdx.x * 256 + threadIdx.x;
    if (idx < 18432) {
        int off = idx >> 11;            // /2048 (9*2048=18432)
        int rem = idx & 2047;
        int oc = rem >> 5, ic = rem & 31;
        float v = w2[(oc * 32 + ic) * 9 + off];
        _Float16 hx = (_Float16)v;
        w2t_hi[idx] = hx;
        w2t_lo[idx] = (_Float16)(v - (float)hx);
    } else if (idx < 18432 + 114688) {
        int j = idx - 18432;            // fwp: 32 d x 3584 (64 oc x 56)
        int d = j / 3584;
        int rem = j - d * 3584;
        int oc = rem / 56, pos = rem - oc * 56;
        float v = (pos < 49) ? fw[(size_t)d * 3136 + oc * 49 + pos] : 0.f;
        _Float16 hx = (_Float16)v;
        fwp_hi[j] = hx;
        fwp_lo[j] = (_Float16)(v - (float)hx);
    } else if (idx < 18432 + 114688 + 1024) {
        int j = idx - (18432 + 114688);
        int oc = j >> 5, k = j & 31;
        float v = (k < 9) ? w1[oc * 9 + k] : ((k == 9) ? b1[oc] : 0.f);
        _Float16 hx = (_Float16)v;
        w1p_hi[j] = hx;
        w1p_lo[j] = (_Float16)(v - (float)hx);
    }
}

// ---------------------------------------------------------------------------
// conv2 partial pass: rows [ROW0, ROW0+NROWS), 2 m-tiles (oc half `oh`).
// Each B-read pair feeds 6 MFMAs. One-tap-ahead A prefetch; setprio around
// the MFMA block. Pool 2x2 in registers -> pool[2][NROWS/2][4].
// ---------------------------------------------------------------------------
template<int ROW0, int NROWS>
__device__ __forceinline__ void conv2_part(
    const _Float16* __restrict__ w2t_hi, const _Float16* __restrict__ w2t_lo,
    const _Float16* Bbuf_hi, const _Float16* Bbuf_lo,
    int oh, int cl, int clr, int kg,
    const float* __restrict__ b2, float pool[2][4][4])
{
    f32x4 acc[2][NROWS];
    #pragma unroll
    for (int j = 0; j < 2; ++j)
        #pragma unroll
        for (int pr = 0; pr < NROWS; ++pr) acc[j][pr] = (f32x4){0.f, 0.f, 0.f, 0.f};

    const size_t ar0 = (size_t)((2 * oh) * 16 + cl) * 32 + kg * 8;
    const size_t ar1 = (size_t)((2 * oh + 1) * 16 + cl) * 32 + kg * 8;
    f16x8 ah0 = *(const f16x8*)(w2t_hi + ar0);
    f16x8 al0 = *(const f16x8*)(w2t_lo + ar0);
    f16x8 ah1 = *(const f16x8*)(w2t_hi + ar1);
    f16x8 al1 = *(const f16x8*)(w2t_lo + ar1);

    #pragma unroll 1
    for (int off = 0; off < 9; ++off) {
        f16x8 nh0 = ah0, nl0 = al0, nh1 = ah1, nl1 = al1;
        if (off < 8) {
            const size_t d = (size_t)(off + 1) * 2048;   // tap stride 64*32
            nh0 = *(const f16x8*)(w2t_hi + ar0 + d);
            nl0 = *(const f16x8*)(w2t_lo + ar0 + d);
            nh1 = *(const f16x8*)(w2t_hi + ar1 + d);
            nl1 = *(const f16x8*)(w2t_lo + ar1 + d);
        }
        const int ky = off / 3, kx = off - ky * 3;
        const int cbase = (kg * 224 + clr + kx) * 8;
        __builtin_amdgcn_s_setprio(1);
        #pragma unroll
        for (int pr = 0; pr < NROWS; ++pr) {
            const int g = ROW0 + pr + ky;           // global input row 0..15
            if (g >= 1 && g <= 14) {                // ring rows: B==0, skip
                const int addr = cbase + (g - 1) * 128;
                f16x8 b_hi = *(const f16x8*)(Bbuf_hi + addr);
                f16x8 b_lo = *(const f16x8*)(Bbuf_lo + addr);
                acc[0][pr] = __builtin_amdgcn_mfma_f32_16x16x32_f16(ah0, b_hi, acc[0][pr], 0, 0, 0);
                acc[0][pr] = __builtin_amdgcn_mfma_f32_16x16x32_f16(al0, b_hi, acc[0][pr], 0, 0, 0);
                acc[0][pr] = __builtin_amdgcn_mfma_f32_16x16x32_f16(ah0, b_lo, acc[0][pr], 0, 0, 0);
                acc[1][pr] = __builtin_amdgcn_mfma_f32_16x16x32_f16(ah1, b_hi, acc[1][pr], 0, 0, 0);
                acc[1][pr] = __builtin_amdgcn_mfma_f32_16x16x32_f16(al1, b_hi, acc[1][pr], 0, 0, 0);
                acc[1][pr] = __builtin_amdgcn_mfma_f32_16x16x32_f16(ah1, b_lo, acc[1][pr], 0, 0, 0);
            }
        }
        __builtin_amdgcn_s_setprio(0);
        ah0 = nh0; al0 = nl0; ah1 = nh1; al1 = nl1;
    }
    #pragma unroll
    for (int j = 0; j < 2; ++j)
        #pragma unroll
        for (int pp = 0; pp < NROWS / 2; ++pp) {
            f32x4 r0 = acc[j][2 * pp], r1 = acc[j][2 * pp + 1];
            #pragma unroll
            for (int r = 0; r < 4; ++r) {
                const int oc = (2 * oh + j) * 16 + kg * 4 + r;
                float v0 = fmaxf(r0[r], __shfl_xor(r0[r], 1));
                float v1 = fmaxf(r1[r], __shfl_xor(r1[r], 1));
                pool[j][pp][r] = fmaxf(fmaxf(v0, v1) + b2[oc], 0.f);
            }
        }
}

// ---------------------------------------------------------------------------
// Kernel 1: FULLY FUSED conv1+conv2 (split-fp16 MFMA) + FC (v_dot2 split-fp16)
// + hyperbolic MLR head. One block per image; no feat roundtrip to HBM
// (eliminates 2x51MB traffic + the fc_mlr kernel).
// F staging: [oc][60] f16 per plane (stride 60 -> 2-way banks, free); pads
// pos 49..55 zeroed (fwp pads also zero). FC: lane l owns oc=l (49 pos, in
// regs as 28 f16x2/plane); wave w owns h-dims 8w..8w+7; 3-term fdot2;
// butterfly all-reduce -> h in LDS; MLR by 10 threads -> out.
// ---------------------------------------------------------------------------
__global__ __launch_bounds__(256, 4) void conv_fused(
    const float* __restrict__ x,         // (N,1,28,28)
    const _Float16* __restrict__ w1p_hi, // (32,32) taps+bias, K-padded
    const _Float16* __restrict__ w1p_lo,
    const _Float16* __restrict__ w2t_hi, // (9,64,32)
    const _Float16* __restrict__ w2t_lo,
    const float* __restrict__ b2,        // (64,)
    const _Float16* __restrict__ fwp_hi, // (32,3584) padded
    const _Float16* __restrict__ fwp_lo,
    const float* __restrict__ fb,        // (32,)
    const float* __restrict__ hw,        // (10,32)
    const float* __restrict__ hb,        // (10,32)
    float* __restrict__ out)             // (N,10)
{
    __shared__ float4 smem4[2017];                        // 32272 B
    unsigned* in_pad  = (unsigned*)smem4;                 // 900 u32 (hi|lo<<16)
    _Float16* Bbuf_hi = (_Float16*)((char*)smem4 + 3600); // 14336 B
    _Float16* Bbuf_lo = (_Float16*)((char*)smem4 + 17936);// 14336 B (ends 32272)
    _Float16* Fhi     = (_Float16*)smem4;                 // [64][60] = 7680 B (aliased)
    _Float16* Flo     = Fhi + 3840;                       // 7680 B (ends 15360)
    float*    hbuf    = (float*)((char*)smem4 + 15360);   // 32 f32 (ends 15488)

    const int tid  = threadIdx.x;
    const int lane = tid & 63;
    const int wave = tid >> 6;
    const int kg   = lane >> 4;      // 0..3
    const int cl   = lane & 15;      // 0..15
    const int clr  = (cl < 14) ? cl : 13;   // clamped col for conv2 reads
    const int n    = blockIdx.x;

    // Phase AB: zero in_pad perimeter; stage x interior pre-split;
    // zero Bbuf column ring (cols 0,15 x 14 rows x 4 icg).
    for (int i = tid; i < 116; i += 256) {
        int yy, xx;
        if (i < 30)       { yy = 0;          xx = i; }
        else if (i < 60)  { yy = 29;         xx = i - 30; }
        else if (i < 88)  { yy = i - 60 + 1; xx = 0; }
        else              { yy = i - 88 + 1; xx = 29; }
        in_pad[yy * 30 + xx] = 0u;
    }
    const float* xin = x + (size_t)n * 784;
    for (int i = tid; i < 784; i += 256) {
        int yy = i / 28, xx = i - yy * 28;
        float v = xin[i];
        _Float16 hx = (_Float16)v;
        _Float16 lx = (_Float16)(v - (float)hx);
        unsigned hb_ = *(const unsigned short*)&hx;
        unsigned lb_ = *(const unsigned short*)&lx;
        in_pad[(yy + 1) * 30 + (xx + 1)] = hb_ | (lb_ << 16);
    }
    if (tid < 112) {
        int icg = tid / 28, j = tid - icg * 28;
        int row = j >> 1, col = (j & 1) ? 15 : 0;
        int c = (icg * 224 + row * 16 + col) * 8;
        *(f32x4*)(Bbuf_hi + c) = (f32x4){0.f, 0.f, 0.f, 0.f};
        *(f32x4*)(Bbuf_lo + c) = (f32x4){0.f, 0.f, 0.f, 0.f};
    }
    __syncthreads();

    // Phase C: conv1 via MFMA (A = w1p taps+bias; B from pre-split in_pad).
    {
        f16x8 a1h[2], a1l[2];
        #pragma unroll
        for (int m = 0; m < 2; ++m) {
            a1h[m] = *(const f16x8*)(w1p_hi + (m * 16 + cl) * 32 + kg * 8);
            a1l[m] = *(const f16x8*)(w1p_lo + (m * 16 + cl) * 32 + kg * 8);
        }
        const int o0 = (kg == 0) ? 0  : ((kg == 1) ? 62 : 0);
        const int o1 = (kg == 0) ? 1  : 0;
        const int o2 = (kg == 0) ? 2  : 0;
        const int o3 = (kg == 0) ? 30 : 0;
        const int o4 = (kg == 0) ? 31 : 0;
        const int o5 = (kg == 0) ? 32 : 0;
        const int o6 = (kg == 0) ? 60 : 0;
        const int o7 = (kg == 0) ? 61 : 0;

        const bool wr = ((cl & 1) == 0) && (cl < 14);

        #pragma unroll 1
        for (int u = 0; u < 7; ++u) {
            const int unit = wave * 7 + u;            // 0..27
            const int rp = unit >> 1, hx = unit & 1;  // pooled row, row half
            const int xcol = hx * 14 + cl;
            f16x8 bh[2], bl[2];
            #pragma unroll
            for (int r2 = 0; r2 < 2; ++r2) {          // conv rows 2rp, 2rp+1
                const int base = (2 * rp + r2) * 30 + xcol;
                unsigned v0 = in_pad[base + o0], v1 = in_pad[base + o1];
                unsigned v2 = in_pad[base + o2], v3 = in_pad[base + o3];
                unsigned v4 = in_pad[base + o4], v5 = in_pad[base + o5];
                unsigned v6 = in_pad[base + o6], v7 = in_pad[base + o7];
                unsigned h01 = (v0 & 0xFFFFu) | (v1 << 16);
                unsigned h23 = (v2 & 0xFFFFu) | (v3 << 16);
                unsigned h45 = (v4 & 0xFFFFu) | (v5 << 16);
                unsigned h67 = (v6 & 0xFFFFu) | (v7 << 16);
                unsigned l01 = (v0 >> 16) | (v1 & 0xFFFF0000u);
                unsigned l23 = (v2 >> 16) | (v3 & 0xFFFF0000u);
                unsigned l45 = (v4 >> 16) | (v5 & 0xFFFF0000u);
                unsigned l67 = (v6 >> 16) | (v7 & 0xFFFF0000u);
                if (kg == 1) {
                    h01 = (h01 & 0xFFFFu) | 0x3C000000u;   // k=9: B_hi=1.0
                    l01 = (l01 & 0xFFFFu);                 //        B_lo=0
                    h23 = h45 = h67 = 0u; l23 = l45 = l67 = 0u;
                } else if (kg >= 2) {
                    h01 = h23 = h45 = h67 = 0u;
                    l01 = l23 = l45 = l67 = 0u;
                }
                union { unsigned uu[4]; f16x8 v; } uh, ul;
                uh.uu[0] = h01; uh.uu[1] = h23; uh.uu[2] = h45; uh.uu[3] = h67;
                ul.uu[0] = l01; ul.uu[1] = l23; ul.uu[2] = l45; ul.uu[3] = l67;
                bh[r2] = uh.v; bl[r2] = ul.v;
            }
            #pragma unroll
            for (int m = 0; m < 2; ++m) {
                f32x4 a0 = (f32x4){0.f, 0.f, 0.f, 0.f};
                f32x4 a1 = (f32x4){0.f, 0.f, 0.f, 0.f};
                a0 = __builtin_amdgcn_mfma_f32_16x16x32_f16(a1h[m], bh[0], a0, 0, 0, 0);
                a0 = __builtin_amdgcn_mfma_f32_16x16x32_f16(a1l[m], bh[0], a0, 0, 0, 0);
                a0 = __builtin_amdgcn_mfma_f32_16x16x32_f16(a1h[m], bl[0], a0, 0, 0, 0);
                a1 = __builtin_amdgcn_mfma_f32_16x16x32_f16(a1h[m], bh[1], a1, 0, 0, 0);
                a1 = __builtin_amdgcn_mfma_f32_16x16x32_f16(a1l[m], bh[1], a1, 0, 0, 0);
                a1 = __builtin_amdgcn_mfma_f32_16x16x32_f16(a1h[m], bl[1], a1, 0, 0, 0);
                float pv[4];
                #pragma unroll
                for (int r = 0; r < 4; ++r) {
                    float vp = fmaxf(a0[r], a1[r]);
                    float hp = fmaxf(vp, __shfl_xor(vp, 1));
                    pv[r] = fmaxf(hp, 0.f);
                }
                union { unsigned short s[4]; f16x4 v; } ph, pl;
                #pragma unroll
                for (int r = 0; r < 4; ++r) {
                    _Float16 mh = (_Float16)pv[r];
                    _Float16 ml = (_Float16)(pv[r] - (float)mh);
                    ph.s[r] = *(const unsigned short*)&mh;
                    pl.s[r] = *(const unsigned short*)&ml;
                }
                if (wr) {
                    const int px2 = hx * 7 + (cl >> 1);
                    const int cell = ((m * 2 + (kg >> 1)) * 224 +
                                      rp * 16 + (px2 + 1)) * 8 + (kg & 1) * 4;
                    *(f16x4*)(Bbuf_hi + cell) = ph.v;
                    *(f16x4*)(Bbuf_lo + cell) = pl.v;
                }
            }
        }
    }
    __syncthreads();

    // Phase D: 2x2 split conv2. rh = wave>>1 (rows 0-7 / 8-13), oh = wave&1.
    const int oh = wave & 1;
    const int rh = wave >> 1;

    float pool[2][4][4];                 // [m-tile j][pool row][reg]
    if (rh == 0)
        conv2_part<0, 8>(w2t_hi, w2t_lo, Bbuf_hi, Bbuf_lo, oh, cl, clr, kg, b2, pool);
    else
        conv2_part<8, 6>(w2t_hi, w2t_lo, Bbuf_hi, Bbuf_lo, oh, cl, clr, kg, b2, pool);
    __syncthreads();   // all Bbuf reads done -> F may alias base

    // Write split F (stride 60) + zero pads pos 49..55.
    {
        const bool wlane = ((cl & 1) == 0) && (cl < 14);
        const int px2 = cl >> 1;
        const int npp = (rh == 0) ? 4 : 3;
        #pragma unroll
        for (int j = 0; j < 2; ++j) {
            #pragma unroll
            for (int pp = 0; pp < 4; ++pp) {
                if (pp < npp) {                   // wave-uniform
                    const int prow = rh * 4 + pp; // pooled row 0..6
                    #pragma unroll
                    for (int r = 0; r < 4; ++r) {
                        const int oc = (2 * oh + j) * 16 + kg * 4 + r;
                        float mq = pool[j][pp][r];
                        _Float16 mh = (_Float16)mq;
                        _Float16 ml = (_Float16)(mq - (float)mh);
                        if (wlane) {
                            int o = oc * 60 + prow * 7 + px2;
                            Fhi[o] = mh; Flo[o] = ml;
                        }
                    }
                }
            }
        }
        for (int i = tid; i < 896; i += 256) {   // zero pads: 2 planes x 64 oc x 7
            int plane = i / 448, j = i - plane * 448;
            int oc = j / 7, p = j - oc * 7;
            (plane ? Flo : Fhi)[oc * 60 + 49 + p] = (_Float16)0.f;
        }
    }
    __syncthreads();   // F complete

    // Fused FC: lane l owns oc=l; wave w owns h-dims 8w..8w+7. 3-term fdot2.
    {
        f16x2 Fh[28], Fl[28];
        {
            const f16x2* fhp = (const f16x2*)(Fhi + lane * 60);
            const f16x2* flp = (const f16x2*)(Flo + lane * 60);
            #pragma unroll
            for (int i = 0; i < 28; ++i) { Fh[i] = fhp[i]; Fl[i] = flp[i]; }
        }
        float hp[8];
        #pragma unroll 1
        for (int d = 0; d < 8; ++d) {
            const int dd = wave * 8 + d;
            const f16x2* whp = (const f16x2*)(fwp_hi + (size_t)dd * 3584 + lane * 56);
            const f16x2* wlp = (const f16x2*)(fwp_lo + (size_t)dd * 3584 + lane * 56);
            float s = 0.f;
            #pragma unroll
            for (int i = 0; i < 28; ++i) {
                f16x2 a = whp[i], b = wlp[i];
                s = __builtin_amdgcn_fdot2(Fh[i], a, s, false);
                s = __builtin_amdgcn_fdot2(Fl[i], a, s, false);
                s = __builtin_amdgcn_fdot2(Fh[i], b, s, false);
            }
            hp[d] = s;
        }
        #pragma unroll
        for (int d = 0; d < 8; ++d) {
            float v = hp[d];
            #pragma unroll
            for (int m = 1; m < 64; m <<= 1) v += __shfl_xor(v, m);
            hp[d] = v;
        }
        if (lane == 0) {
            #pragma unroll
            for (int d = 0; d < 8; ++d) hbuf[wave * 8 + d] = hp[d] + fb[wave * 8 + d];
        }
    }
    __syncthreads();

    // MLR head: 10 outputs for this image, fp32.
    if (tid < 10) {
        const int k = tid;
        const float* xr = hbuf;
        const float* wr = hw + k * 32;
        const float* br = hb + k * 32;
        float x2 = 0.f, b2s = 0.f, ww = 0.f, xb = 0.f, xw = 0.f, wb = 0.f;
        #pragma unroll
        for (int i = 0; i < 32; ++i) {
            float xi = xr[i], wi = wr[i], bi = br[i];
            x2 += xi * xi;  b2s += bi * bi;  ww += wi * wi;
            xb += xi * bi;  xw += xi * wi;   wb += wi * bi;
        }
        float w_norm = sqrtf(ww);
        float wnc = fmaxf(w_norm, 1e-12f);
        float inner = -xb;
        float a_num = 1.f + 2.f * inner + x2;
        float b_num = 1.f - b2s;
        float den = 1.f + 2.f * inner + x2 * b2s;
        float alpha = a_num / fmaxf(den, EPSV);
        float beta = b_num / den;                 // raw denom, as in source
        float mob2 = alpha * alpha * b2s + 2.f * alpha * beta * inner + beta * beta * x2;
        float sq = sqrtf(mob2);
        const float MAXN = (float)(1.0 - 1e-5);
        const float MAXN2 = (float)((1.0 - 1e-5) * (1.0 - 1e-5));
        float normalizer = (sq > MAXN) ? (MAXN / fmaxf(sq, EPSV)) : 1.f;
        float mob2c = (sq < MAXN) ? mob2 : MAXN2;
        float hyper = (alpha * (-wb) + beta * xw) / wnc;
        hyper *= normalizer;
        float asin_in = 2.f * hyper / fmaxf(1.f - mob2c, EPSV);
        float scaler = 2.f / fmaxf(1.f - b2s, EPSV);
        out[(size_t)n * 10 + k] = scaler * w_norm * asinhf(asin_in);
    }
}

// ---------------------------------------------------------------------------
extern "C" void kernel_launch(void* const* d_in, const int* in_sizes, int n_in,
                              void* d_out, int out_size, void* d_ws, size_t ws_size,
                              hipStream_t stream) {
    const float* x   = (const float*)d_in[0];
    const float* w1  = (const float*)d_in[1];
    const float* b1  = (const float*)d_in[2];
    const float* w2  = (const float*)d_in[3];
    const float* b2  = (const float*)d_in[4];
    const float* fw  = (const float*)d_in[5];
    const float* fb  = (const float*)d_in[6];
    const float* hw  = (const float*)d_in[7];
    const float* hb  = (const float*)d_in[8];
    float* out = (float*)d_out;

    const int N = 4096;
    char* ws = (char*)d_ws;
    _Float16* w2t_hi = (_Float16*)ws;                    //  36,864 B
    _Float16* w2t_lo = (_Float16*)(ws + 36864);          //  36,864 B
    _Float16* fwp_hi = (_Float16*)(ws + 73728);          // 229,376 B
    _Float16* fwp_lo = (_Float16*)(ws + 303104);         // 229,376 B
    _Float16* w1p_hi = (_Float16*)(ws + 532480);         //   2,048 B
    _Float16* w1p_lo = (_Float16*)(ws + 534528);         //   2,048 B (end 536,576)

    prep_weights<<<(18432 + 114688 + 1024 + 255) / 256, 256, 0, stream>>>(
        w1, b1, w2, fw, w2t_hi, w2t_lo, fwp_hi, fwp_lo, w1p_hi, w1p_lo);
    conv_fused<<<N, 256, 0, stream>>>(x, w1p_hi, w1p_lo, w2t_hi, w2t_lo, b2,
                                      fwp_hi, fwp_lo, fb, hw, hb, out);
}

// Round 18
// 131.564 us; speedup vs baseline: 3.2024x; 3.2024x over previous
//
#include <hip/hip_runtime.h>
#include <math.h>

#define EPSV 1e-5f

typedef _Float16 f16x8 __attribute__((ext_vector_type(8)));
typedef _Float16 f16x4 __attribute__((ext_vector_type(4)));
typedef float f32x4 __attribute__((ext_vector_type(4)));

// ---------------------------------------------------------------------------
// Kernel 0: weight prep -> split-fp16 (hi,lo) pairs.
// w2t[off][oc][ic] (9,64,32); fw (32,3136); w1p[oc][k32] taps 0-8, bias k=9.
// ---------------------------------------------------------------------------
__global__ __launch_bounds__(256) void prep_weights(
    const float* __restrict__ w1, const float* __restrict__ b1,
    const float* __restrict__ w2, const float* __restrict__ fw,
    _Float16* __restrict__ w2t_hi, _Float16* __restrict__ w2t_lo,
    _Float16* __restrict__ fw_hi,  _Float16* __restrict__ fw_lo,
    _Float16* __restrict__ w1p_hi, _Float16* __restrict__ w1p_lo)
{
    int idx = blockIdx.x * 256 + threadIdx.x;
    if (idx < 18432) {
        int off = idx >> 11;            // /2048 (9*2048=18432)
        int rem = idx & 2047;
        int oc = rem >> 5, ic = rem & 31;
        float v = w2[(oc * 32 + ic) * 9 + off];
        _Float16 hx = (_Float16)v;
        w2t_hi[idx] = hx;
        w2t_lo[idx] = (_Float16)(v - (float)hx);
    } else if (idx < 18432 + 100352) {
        int j = idx - 18432;
        float v = fw[j];
        _Float16 hx = (_Float16)v;
        fw_hi[j] = hx;
        fw_lo[j] = (_Float16)(v - (float)hx);
    } else if (idx < 18432 + 100352 + 1024) {
        int j = idx - (18432 + 100352);
        int oc = j >> 5, k = j & 31;
        float v = (k < 9) ? w1[oc * 9 + k] : ((k == 9) ? b1[oc] : 0.f);
        _Float16 hx = (_Float16)v;
        w1p_hi[j] = hx;
        w1p_lo[j] = (_Float16)(v - (float)hx);
    }
}

// ---------------------------------------------------------------------------
// conv2 partial pass: rows [ROW0, ROW0+NROWS), 2 m-tiles (oc half `oh`).
// Each B-read pair feeds 6 MFMAs (2 m-tiles x 3 split terms).
// ONE-TAP-AHEAD A prefetch hides the ~200cy L2 latency (w2t 72KB > 32KB L1)
// under the tap's MFMA block. s_setprio(1) wraps the MFMA block (T5).
// Pool 2x2 in registers -> pool[2][NROWS/2][4]. No LDS writes, no barriers.
// ---------------------------------------------------------------------------
template<int ROW0, int NROWS>
__device__ __forceinline__ void conv2_part(
    const _Float16* __restrict__ w2t_hi, const _Float16* __restrict__ w2t_lo,
    const _Float16* Bbuf_hi, const _Float16* Bbuf_lo,
    int oh, int cl, int clr, int kg,
    const float* __restrict__ b2, float pool[2][4][4])
{
    f32x4 acc[2][NROWS];
    #pragma unroll
    for (int j = 0; j < 2; ++j)
        #pragma unroll
        for (int pr = 0; pr < NROWS; ++pr) acc[j][pr] = (f32x4){0.f, 0.f, 0.f, 0.f};

    const size_t ar0 = (size_t)((2 * oh) * 16 + cl) * 32 + kg * 8;
    const size_t ar1 = (size_t)((2 * oh + 1) * 16 + cl) * 32 + kg * 8;
    f16x8 ah0 = *(const f16x8*)(w2t_hi + ar0);
    f16x8 al0 = *(const f16x8*)(w2t_lo + ar0);
    f16x8 ah1 = *(const f16x8*)(w2t_hi + ar1);
    f16x8 al1 = *(const f16x8*)(w2t_lo + ar1);

    #pragma unroll 1
    for (int off = 0; off < 9; ++off) {
        // Prefetch next tap's A-frags (issued before this tap's MFMAs).
        f16x8 nh0 = ah0, nl0 = al0, nh1 = ah1, nl1 = al1;
        if (off < 8) {
            const size_t d = (size_t)(off + 1) * 2048;   // tap stride 64*32
            nh0 = *(const f16x8*)(w2t_hi + ar0 + d);
            nl0 = *(const f16x8*)(w2t_lo + ar0 + d);
            nh1 = *(const f16x8*)(w2t_hi + ar1 + d);
            nl1 = *(const f16x8*)(w2t_lo + ar1 + d);
        }
        const int ky = off / 3, kx = off - ky * 3;
        const int cbase = (kg * 224 + clr + kx) * 8;
        __builtin_amdgcn_s_setprio(1);
        #pragma unroll
        for (int pr = 0; pr < NROWS; ++pr) {
            const int g = ROW0 + pr + ky;           // global input row 0..15
            if (g >= 1 && g <= 14) {                // ring rows: B==0, skip
                const int addr = cbase + (g - 1) * 128;
                f16x8 b_hi = *(const f16x8*)(Bbuf_hi + addr);
                f16x8 b_lo = *(const f16x8*)(Bbuf_lo + addr);
                acc[0][pr] = __builtin_amdgcn_mfma_f32_16x16x32_f16(ah0, b_hi, acc[0][pr], 0, 0, 0);
                acc[0][pr] = __builtin_amdgcn_mfma_f32_16x16x32_f16(al0, b_hi, acc[0][pr], 0, 0, 0);
                acc[0][pr] = __builtin_amdgcn_mfma_f32_16x16x32_f16(ah0, b_lo, acc[0][pr], 0, 0, 0);
                acc[1][pr] = __builtin_amdgcn_mfma_f32_16x16x32_f16(ah1, b_hi, acc[1][pr], 0, 0, 0);
                acc[1][pr] = __builtin_amdgcn_mfma_f32_16x16x32_f16(al1, b_hi, acc[1][pr], 0, 0, 0);
                acc[1][pr] = __builtin_amdgcn_mfma_f32_16x16x32_f16(ah1, b_lo, acc[1][pr], 0, 0, 0);
            }
        }
        __builtin_amdgcn_s_setprio(0);
        ah0 = nh0; al0 = nl0; ah1 = nh1; al1 = nl1;
    }
    // Pool 2x2: horizontal partner = lane cl^1, vertical = acc row pair.
    #pragma unroll
    for (int j = 0; j < 2; ++j)
        #pragma unroll
        for (int pp = 0; pp < NROWS / 2; ++pp) {
            f32x4 r0 = acc[j][2 * pp], r1 = acc[j][2 * pp + 1];
            #pragma unroll
            for (int r = 0; r < 4; ++r) {
                const int oc = (2 * oh + j) * 16 + kg * 4 + r;
                float v0 = fmaxf(r0[r], __shfl_xor(r0[r], 1));
                float v1 = fmaxf(r1[r], __shfl_xor(r1[r], 1));
                pool[j][pp][r] = fmaxf(fmaxf(v0, v1) + b2[oc], 0.f);
            }
        }
}

// ---------------------------------------------------------------------------
// Kernel 1: conv1 AND conv2 via split-fp16 MFMA. One block per image, 4 waves,
// 4 blocks/CU (hard HW ceiling — round-14 evidence; occupancy work closed).
// Phase C: 28 (rp,hx) units flattened, 7 per wave (balanced).
// Phase D: 2x2 wave split (rh = row half, oh = oc half); B-pair feeds 6 MFMAs.
// LDS 32272 B (stride-16 Bbuf). Ring rows implicit zeros (tap-visits skipped).
// F staging (12544 B) aliases the base after the post-conv2 barrier.
// ---------------------------------------------------------------------------
__global__ __launch_bounds__(256, 4) void conv_fused(
    const float* __restrict__ x,         // (N,1,28,28)
    const _Float16* __restrict__ w1p_hi, // (32,32) taps+bias, K-padded
    const _Float16* __restrict__ w1p_lo,
    const _Float16* __restrict__ w2t_hi, // (9,64,32)
    const _Float16* __restrict__ w2t_lo,
    const float* __restrict__ b2,        // (64,)
    _Float16* __restrict__ feat_hi,      // (N,3136)
    _Float16* __restrict__ feat_lo)      // (N,3136)
{
    __shared__ float4 smem4[2017];                        // 32272 B
    unsigned* in_pad  = (unsigned*)smem4;                 // 900 u32 (hi|lo<<16)
    _Float16* Bbuf_hi = (_Float16*)((char*)smem4 + 3600); // 14336 B
    _Float16* Bbuf_lo = (_Float16*)((char*)smem4 + 17936);// 14336 B (ends 32272)
    _Float16* Fhi     = (_Float16*)smem4;                 // 6272 B (aliased, post-barrier)
    _Float16* Flo     = Fhi + 3136;                       // 6272 B (ends 12544)

    const int tid  = threadIdx.x;
    const int lane = tid & 63;
    const int wave = tid >> 6;
    const int kg   = lane >> 4;      // 0..3
    const int cl   = lane & 15;      // 0..15
    const int clr  = (cl < 14) ? cl : 13;   // clamped col for conv2 reads
    const int n    = blockIdx.x;

    // Phase AB: zero in_pad perimeter; stage x interior pre-split;
    // zero Bbuf column ring (cols 0,15 x 14 rows x 4 icg = 112 cells).
    for (int i = tid; i < 116; i += 256) {
        int yy, xx;
        if (i < 30)       { yy = 0;          xx = i; }
        else if (i < 60)  { yy = 29;         xx = i - 30; }
        else if (i < 88)  { yy = i - 60 + 1; xx = 0; }
        else              { yy = i - 88 + 1; xx = 29; }
        in_pad[yy * 30 + xx] = 0u;
    }
    const float* xin = x + (size_t)n * 784;
    for (int i = tid; i < 784; i += 256) {
        int yy = i / 28, xx = i - yy * 28;
        float v = xin[i];
        _Float16 hx = (_Float16)v;
        _Float16 lx = (_Float16)(v - (float)hx);
        unsigned hb = *(const unsigned short*)&hx;
        unsigned lb = *(const unsigned short*)&lx;
        in_pad[(yy + 1) * 30 + (xx + 1)] = hb | (lb << 16);
    }
    if (tid < 112) {
        int icg = tid / 28, j = tid - icg * 28;
        int row = j >> 1, col = (j & 1) ? 15 : 0;
        int c = (icg * 224 + row * 16 + col) * 8;
        *(f32x4*)(Bbuf_hi + c) = (f32x4){0.f, 0.f, 0.f, 0.f};
        *(f32x4*)(Bbuf_lo + c) = (f32x4){0.f, 0.f, 0.f, 0.f};
    }
    __syncthreads();

    // Phase C: conv1 via MFMA (A = w1p taps+bias; B from pre-split in_pad).
    // 28 (rp,hx) units, 7 per wave -> balanced.
    {
        f16x8 a1h[2], a1l[2];
        #pragma unroll
        for (int m = 0; m < 2; ++m) {
            a1h[m] = *(const f16x8*)(w1p_hi + (m * 16 + cl) * 32 + kg * 8);
            a1l[m] = *(const f16x8*)(w1p_lo + (m * 16 + cl) * 32 + kg * 8);
        }
        const int o0 = (kg == 0) ? 0  : ((kg == 1) ? 62 : 0);
        const int o1 = (kg == 0) ? 1  : 0;
        const int o2 = (kg == 0) ? 2  : 0;
        const int o3 = (kg == 0) ? 30 : 0;
        const int o4 = (kg == 0) ? 31 : 0;
        const int o5 = (kg == 0) ? 32 : 0;
        const int o6 = (kg == 0) ? 60 : 0;
        const int o7 = (kg == 0) ? 61 : 0;

        const bool wr = ((cl & 1) == 0) && (cl < 14);

        #pragma unroll 1
        for (int u = 0; u < 7; ++u) {
            const int unit = wave * 7 + u;            // 0..27
            const int rp = unit >> 1, hx = unit & 1;  // pooled row, row half
            const int xcol = hx * 14 + cl;
            f16x8 bh[2], bl[2];
            #pragma unroll
            for (int r2 = 0; r2 < 2; ++r2) {          // conv rows 2rp, 2rp+1
                const int base = (2 * rp + r2) * 30 + xcol;
                unsigned v0 = in_pad[base + o0], v1 = in_pad[base + o1];
                unsigned v2 = in_pad[base + o2], v3 = in_pad[base + o3];
                unsigned v4 = in_pad[base + o4], v5 = in_pad[base + o5];
                unsigned v6 = in_pad[base + o6], v7 = in_pad[base + o7];
                unsigned h01 = (v0 & 0xFFFFu) | (v1 << 16);
                unsigned h23 = (v2 & 0xFFFFu) | (v3 << 16);
                unsigned h45 = (v4 & 0xFFFFu) | (v5 << 16);
                unsigned h67 = (v6 & 0xFFFFu) | (v7 << 16);
                unsigned l01 = (v0 >> 16) | (v1 & 0xFFFF0000u);
                unsigned l23 = (v2 >> 16) | (v3 & 0xFFFF0000u);
                unsigned l45 = (v4 >> 16) | (v5 & 0xFFFF0000u);
                unsigned l67 = (v6 >> 16) | (v7 & 0xFFFF0000u);
                if (kg == 1) {
                    h01 = (h01 & 0xFFFFu) | 0x3C000000u;   // k=9: B_hi=1.0
                    l01 = (l01 & 0xFFFFu);                 //        B_lo=0
                    h23 = h45 = h67 = 0u; l23 = l45 = l67 = 0u;
                } else if (kg >= 2) {
                    h01 = h23 = h45 = h67 = 0u;
                    l01 = l23 = l45 = l67 = 0u;
                }
                union { unsigned uu[4]; f16x8 v; } uh, ul;
                uh.uu[0] = h01; uh.uu[1] = h23; uh.uu[2] = h45; uh.uu[3] = h67;
                ul.uu[0] = l01; ul.uu[1] = l23; ul.uu[2] = l45; ul.uu[3] = l67;
                bh[r2] = uh.v; bl[r2] = ul.v;
            }
            #pragma unroll
            for (int m = 0; m < 2; ++m) {
                f32x4 a0 = (f32x4){0.f, 0.f, 0.f, 0.f};
                f32x4 a1 = (f32x4){0.f, 0.f, 0.f, 0.f};
                a0 = __builtin_amdgcn_mfma_f32_16x16x32_f16(a1h[m], bh[0], a0, 0, 0, 0);
                a0 = __builtin_amdgcn_mfma_f32_16x16x32_f16(a1l[m], bh[0], a0, 0, 0, 0);
                a0 = __builtin_amdgcn_mfma_f32_16x16x32_f16(a1h[m], bl[0], a0, 0, 0, 0);
                a1 = __builtin_amdgcn_mfma_f32_16x16x32_f16(a1h[m], bh[1], a1, 0, 0, 0);
                a1 = __builtin_amdgcn_mfma_f32_16x16x32_f16(a1l[m], bh[1], a1, 0, 0, 0);
                a1 = __builtin_amdgcn_mfma_f32_16x16x32_f16(a1h[m], bl[1], a1, 0, 0, 0);
                float pv[4];
                #pragma unroll
                for (int r = 0; r < 4; ++r) {
                    float vp = fmaxf(a0[r], a1[r]);
                    float hp = fmaxf(vp, __shfl_xor(vp, 1));
                    pv[r] = fmaxf(hp, 0.f);
                }
                union { unsigned short s[4]; f16x4 v; } ph, pl;
                #pragma unroll
                for (int r = 0; r < 4; ++r) {
                    _Float16 mh = (_Float16)pv[r];
                    _Float16 ml = (_Float16)(pv[r] - (float)mh);
                    ph.s[r] = *(const unsigned short*)&mh;
                    pl.s[r] = *(const unsigned short*)&ml;
                }
                if (wr) {
                    const int px2 = hx * 7 + (cl >> 1);
                    const int cell = ((m * 2 + (kg >> 1)) * 224 +
                                      rp * 16 + (px2 + 1)) * 8 + (kg & 1) * 4;
                    *(f16x4*)(Bbuf_hi + cell) = ph.v;
                    *(f16x4*)(Bbuf_lo + cell) = pl.v;
                }
            }
        }
    }
    __syncthreads();

    // Phase D: 2x2 split conv2. rh = wave>>1 (rows 0-7 / 8-13), oh = wave&1.
    const int oh = wave & 1;
    const int rh = wave >> 1;

    float pool[2][4][4];                 // [m-tile j][pool row][reg]
    if (rh == 0)
        conv2_part<0, 8>(w2t_hi, w2t_lo, Bbuf_hi, Bbuf_lo, oh, cl, clr, kg, b2, pool);
    else
        conv2_part<8, 6>(w2t_hi, w2t_lo, Bbuf_hi, Bbuf_lo, oh, cl, clr, kg, b2, pool);
    __syncthreads();   // all Bbuf reads done -> F may alias base

    // Write split F: wave (rh,oh) owns pooled rows rh*4.., ocs 2oh*16..
    {
        const bool wlane = ((cl & 1) == 0) && (cl < 14);
        const int px2 = cl >> 1;
        const int npp = (rh == 0) ? 4 : 3;
        #pragma unroll
        for (int j = 0; j < 2; ++j) {
            #pragma unroll
            for (int pp = 0; pp < 4; ++pp) {
                if (pp < npp) {                   // wave-uniform
                    const int prow = rh * 4 + pp; // pooled row 0..6
                    #pragma unroll
                    for (int r = 0; r < 4; ++r) {
                        const int oc = (2 * oh + j) * 16 + kg * 4 + r;
                        float mq = pool[j][pp][r];
                        _Float16 mh = (_Float16)mq;
                        _Float16 ml = (_Float16)(mq - (float)mh);
                        if (wlane) {
                            int o = oc * 49 + prow * 7 + px2;
                            Fhi[o] = mh; Flo[o] = ml;
                        }
                    }
                }
            }
        }
    }
    __syncthreads();

    // Coalesced dump: 1568 dwords per plane
    unsigned* gh = (unsigned*)(feat_hi + (size_t)n * 3136);
    unsigned* gl = (unsigned*)(feat_lo + (size_t)n * 3136);
    const unsigned* sh = (const unsigned*)Fhi;
    const unsigned* sl = (const unsigned*)Flo;
    for (int i = tid; i < 1568; i += 256) { gh[i] = sh[i]; gl[i] = sl[i]; }
}

// ---------------------------------------------------------------------------
// Kernel 2: fused FC (split-fp16 MFMA) + hyperbolic MLR head.
// 256 blocks x 1024 threads (16 waves — 4 waves/SIMD for the HBM-bound
// 51MB feat stream). Block = 16-image M-tile; 16 waves split K (7/7/6x14 of
// 98 k-steps), combine in LDS, then MLR on the LDS h-tile.
// ---------------------------------------------------------------------------
__global__ __launch_bounds__(1024) void fc_mlr(
    const _Float16* __restrict__ feat_hi, const _Float16* __restrict__ feat_lo,
    const _Float16* __restrict__ fw_hi,   const _Float16* __restrict__ fw_lo,
    const float* __restrict__ fb,
    const float* __restrict__ hw,   // (10,32)
    const float* __restrict__ hb,   // (10,32)
    float* __restrict__ out)        // (N,10)
{
    __shared__ float part[16][64][9];   // padded: stride 9 -> conflict-free
    __shared__ float Ht[16][33];

    const int tid  = threadIdx.x;
    const int lane = tid & 63;
    const int wave = tid >> 6;         // 0..15
    const int kg = lane >> 4, cl = lane & 15;
    const int m0 = blockIdx.x * 16;

    const int start = (wave < 2) ? wave * 7 : 14 + (wave - 2) * 6;
    const int nstep = (wave < 2) ? 7 : 6;
    const size_t koff = (size_t)start * 32 + kg * 8;

    const _Float16* ah  = feat_hi + (size_t)(m0 + cl) * 3136 + koff;
    const _Float16* al  = feat_lo + (size_t)(m0 + cl) * 3136 + koff;
    const _Float16* b0h = fw_hi + (size_t)cl * 3136 + koff;
    const _Float16* b0l = fw_lo + (size_t)cl * 3136 + koff;
    const _Float16* b1h = fw_hi + (size_t)(16 + cl) * 3136 + koff;
    const _Float16* b1l = fw_lo + (size_t)(16 + cl) * 3136 + koff;

    f32x4 acc0 = {0.f, 0.f, 0.f, 0.f}, acc1 = {0.f, 0.f, 0.f, 0.f};
    for (int s = 0; s < nstep; ++s) {
        int k0 = s * 32;
        f16x8 vah = *(const f16x8*)(ah + k0);
        f16x8 val_ = *(const f16x8*)(al + k0);
        f16x8 v0h = *(const f16x8*)(b0h + k0);
        f16x8 v0l = *(const f16x8*)(b0l + k0);
        f16x8 v1h = *(const f16x8*)(b1h + k0);
        f16x8 v1l = *(const f16x8*)(b1l + k0);
        acc0 = __builtin_amdgcn_mfma_f32_16x16x32_f16(vah, v0h, acc0, 0, 0, 0);
        acc0 = __builtin_amdgcn_mfma_f32_16x16x32_f16(val_, v0h, acc0, 0, 0, 0);
        acc0 = __builtin_amdgcn_mfma_f32_16x16x32_f16(vah, v0l, acc0, 0, 0, 0);
        acc1 = __builtin_amdgcn_mfma_f32_16x16x32_f16(vah, v1h, acc1, 0, 0, 0);
        acc1 = __builtin_amdgcn_mfma_f32_16x16x32_f16(val_, v1h, acc1, 0, 0, 0);
        acc1 = __builtin_amdgcn_mfma_f32_16x16x32_f16(vah, v1l, acc1, 0, 0, 0);
    }
    #pragma unroll
    for (int r = 0; r < 4; ++r) {
        part[wave][lane][r]     = acc0[r];
        part[wave][lane][4 + r] = acc1[r];
    }
    __syncthreads();

    // Reduce 16 partials -> h tile in LDS. 512 values, threads 0..511.
    if (tid < 512) {
        int col = tid & 31, row = tid >> 5;             // row = image 0..15
        int l  = ((row >> 2) << 4) + (col & 15);
        int rr = ((col >= 16) ? 4 : 0) + (row & 3);
        float s = 0.f;
        #pragma unroll
        for (int w = 0; w < 16; ++w) s += part[w][l][rr];
        Ht[row][col] = s + fb[col];
    }
    __syncthreads();

    // MLR head: 160 outputs (16 images x 10 classes), fp32.
    if (tid < 160) {
        int im = tid / 10, k = tid - im * 10;
        const float* xr = &Ht[im][0];
        const float* wr = hw + k * 32;
        const float* br = hb + k * 32;
        float x2 = 0.f, b2s = 0.f, ww = 0.f, xb = 0.f, xw = 0.f, wb = 0.f;
        #pragma unroll
        for (int i = 0; i < 32; ++i) {
            float xi = xr[i], wi = wr[i], bi = br[i];
            x2 += xi * xi;  b2s += bi * bi;  ww += wi * wi;
            xb += xi * bi;  xw += xi * wi;   wb += wi * bi;
        }
        float w_norm = sqrtf(ww);
        float wnc = fmaxf(w_norm, 1e-12f);
        float inner = -xb;
        float a_num = 1.f + 2.f * inner + x2;
        float b_num = 1.f - b2s;
        float den = 1.f + 2.f * inner + x2 * b2s;
        float alpha = a_num / fmaxf(den, EPSV);
        float beta = b_num / den;                 // raw denom, as in source
        float mob2 = alpha * alpha * b2s + 2.f * alpha * beta * inner + beta * beta * x2;
        float sq = sqrtf(mob2);
        const float MAXN = (float)(1.0 - 1e-5);
        const float MAXN2 = (float)((1.0 - 1e-5) * (1.0 - 1e-5));
        float normalizer = (sq > MAXN) ? (MAXN / fmaxf(sq, EPSV)) : 1.f;
        float mob2c = (sq < MAXN) ? mob2 : MAXN2;
        float hyper = (alpha * (-wb) + beta * xw) / wnc;
        hyper *= normalizer;
        float asin_in = 2.f * hyper / fmaxf(1.f - mob2c, EPSV);
        float scaler = 2.f / fmaxf(1.f - b2s, EPSV);
        out[(size_t)m0 * 10 + tid] = scaler * w_norm * asinhf(asin_in);
    }
}

// ---------------------------------------------------------------------------
extern "C" void kernel_launch(void* const* d_in, const int* in_sizes, int n_in,
                              void* d_out, int out_size, void* d_ws, size_t ws_size,
                              hipStream_t stream) {
    const float* x   = (const float*)d_in[0];
    const float* w1  = (const float*)d_in[1];
    const float* b1  = (const float*)d_in[2];
    const float* w2  = (const float*)d_in[3];
    const float* b2  = (const float*)d_in[4];
    const float* fw  = (const float*)d_in[5];
    const float* fb  = (const float*)d_in[6];
    const float* hw  = (const float*)d_in[7];
    const float* hb  = (const float*)d_in[8];
    float* out = (float*)d_out;

    const int N = 4096;
    char* ws = (char*)d_ws;
    _Float16* feat_hi = (_Float16*)ws;                        // 25,690,112 B
    _Float16* feat_lo = (_Float16*)(ws + 25690112);           // 25,690,112 B
    _Float16* w2t_hi  = (_Float16*)(ws + 51380224);           //     36,864 B
    _Float16* w2t_lo  = (_Float16*)(ws + 51417088);           //     36,864 B
    _Float16* fw_hi   = (_Float16*)(ws + 51453952);           //    200,704 B
    _Float16* fw_lo   = (_Float16*)(ws + 51654656);           //    200,704 B
    _Float16* w1p_hi  = (_Float16*)(ws + 51855360);           //      2,048 B
    _Float16* w1p_lo  = (_Float16*)(ws + 51857408);           //      2,048 B (end 51,859,456)

    prep_weights<<<(18432 + 100352 + 1024 + 255) / 256, 256, 0, stream>>>(
        w1, b1, w2, fw, w2t_hi, w2t_lo, fw_hi, fw_lo, w1p_hi, w1p_lo);
    conv_fused<<<N, 256, 0, stream>>>(x, w1p_hi, w1p_lo, w2t_hi, w2t_lo, b2,
                                      feat_hi, feat_lo);
    fc_mlr<<<N / 16, 1024, 0, stream>>>(feat_hi, feat_lo, fw_hi, fw_lo, fb, hw, hb, out);
}